// Round 1
// baseline (190.103 us; speedup 1.0000x reference)
//
#include <hip/hip_runtime.h>
#include <hip/hip_bf16.h>
#include <stdint.h>

#define N_SAMP 8192
#define D_TOW  128
#define D_HID  128

typedef __bf16 bf16x8 __attribute__((ext_vector_type(8)));
typedef float  f32x4  __attribute__((ext_vector_type(4)));

__device__ __forceinline__ ushort f2bf(float f) {
  union { float f; uint32_t u; } c; c.f = f;
  uint32_t u = c.u;
  return (ushort)((u + 0x7FFFu + ((u >> 16) & 1u)) >> 16);  // RNE
}

// fp32 -> bf16 convert for x and W0, fused binary-input check on x.
__global__ __launch_bounds__(256) void prep_kernel(
    const float* __restrict__ x, const float* __restrict__ w0,
    ushort* __restrict__ xb, ushort* __restrict__ w0b, int* __restrict__ flag) {
  const int NX4 = (N_SAMP * D_TOW) / 4;        // 262144
  const int NW4 = (D_TOW * D_HID * D_TOW) / 4; // 524288
  int t = blockIdx.x * blockDim.x + threadIdx.x;
  if (t < NX4) {
    float4 v = ((const float4*)x)[t];
    bool bad = !(((v.x == 0.f) || (v.x == 1.f)) &&
                 ((v.y == 0.f) || (v.y == 1.f)) &&
                 ((v.z == 0.f) || (v.z == 1.f)) &&
                 ((v.w == 0.f) || (v.w == 1.f)));
    ushort4 o;
    o.x = f2bf(v.x); o.y = f2bf(v.y); o.z = f2bf(v.z); o.w = f2bf(v.w);
    ((ushort4*)xb)[t] = o;
    // one benign racy store per wave with any non-{0,1} element
    if (__ballot(bad) != 0ull && (threadIdx.x & 63) == 0) *flag = 1;
  } else if (t < NX4 + NW4) {
    int j = t - NX4;
    float4 v = ((const float4*)w0)[j];
    ushort4 o;
    o.x = f2bf(v.x); o.y = f2bf(v.y); o.z = f2bf(v.z); o.w = f2bf(v.w);
    ((ushort4*)w0b)[j] = o;
  }
}

__device__ __forceinline__ void g2l16(const void* g, void* l) {
  __builtin_amdgcn_global_load_lds(
      (const __attribute__((address_space(1))) void*)g,
      (__attribute__((address_space(3))) void*)l, 16, 0, 0);
}

// One block = one tower k x one 128-row chunk of samples.
// pre[n,h] = X[128x128] @ W0_k^T  (MFMA, bf16), then fused
// out[n,k] = sum_h W1[k,h]*sigmoid(pre + b0) + b1[k].
__global__ __launch_bounds__(256, 2) void towers_kernel(
    const ushort* __restrict__ xb, const ushort* __restrict__ w0b,
    const float* __restrict__ b0, const float* __restrict__ w1,
    const float* __restrict__ b1, const int* __restrict__ flag,
    float* __restrict__ out) {
  // [row][d], 128 rows x 256 B, 16B chunks XOR-swizzled by (row&15)
  __shared__ __align__(16) ushort sX[128 * 128];
  __shared__ __align__(16) ushort sW[128 * 128];
  __shared__ float sRed[128][2];

  int bid = blockIdx.x;
  int xcd = bid & 7;          // XCD-partition: 16 towers per XCD for L2 locality
  int idx = bid >> 3;
  int k = xcd * 16 + (idx >> 6);
  int n0 = (idx & 63) * 128;

  int tid = threadIdx.x;
  int lane = tid & 63;
  int wave = tid >> 6;

  const ushort* xg = xb + n0 * 128;          // [128][128] row-major bf16
  const ushort* wg = w0b + k * (128 * 128);  // W0_k: [h][d] row-major bf16

  // Stage both tiles: 8 wave-instructions x 1KB each per wave per tile.
  // LDS dest = uniform base + lane*16 (hardware rule); swizzle goes on the
  // global source chunk index instead (same 256B segments -> still coalesced).
#pragma unroll
  for (int i = 0; i < 8; ++i) {
    int base = wave * 8192 + i * 1024;  // byte offset, wave-uniform
    int L = base + lane * 16;
    int row = L >> 8;
    int ch = (L >> 4) & 15;
    int c = ch ^ (row & 15);
    g2l16(xg + row * 128 + c * 8, (char*)sX + base);
    g2l16(wg + row * 128 + c * 8, (char*)sW + base);
  }
  __syncthreads();  // barrier drains vmcnt -> LDS writes visible

  int q = lane >> 4;      // k-chunk selector within fragment
  int cl = lane & 15;     // row-of-A / col-of-B selector
  int R = (wave >> 1) * 64;   // wave's row quadrant
  int Cc = (wave & 1) * 64;   // wave's col (h) quadrant

  f32x4 acc[4][4];
#pragma unroll
  for (int rf = 0; rf < 4; ++rf)
#pragma unroll
    for (int cf = 0; cf < 4; ++cf)
      acc[rf][cf] = (f32x4){0.f, 0.f, 0.f, 0.f};

#pragma unroll
  for (int t = 0; t < 4; ++t) {  // K = 128 = 4 * 32
    bf16x8 a[4], b[4];
    int ch = (t * 4 + q) ^ cl;   // row&15 == cl, col&15 == cl
#pragma unroll
    for (int rf = 0; rf < 4; ++rf) {
      int row = R + rf * 16 + cl;
      a[rf] = *(const bf16x8*)((const char*)sX + row * 256 + ch * 16);
    }
#pragma unroll
    for (int cf = 0; cf < 4; ++cf) {
      int col = Cc + cf * 16 + cl;
      b[cf] = *(const bf16x8*)((const char*)sW + col * 256 + ch * 16);
    }
#pragma unroll
    for (int rf = 0; rf < 4; ++rf)
#pragma unroll
      for (int cf = 0; cf < 4; ++cf)
        acc[rf][cf] = __builtin_amdgcn_mfma_f32_16x16x32_bf16(
            a[rf], b[cf], acc[rf][cf], 0, 0, 0);
  }

  // Epilogue: sigmoid + weighted h-reduction, all in-register per wave.
  float bb[4], wv[4];
#pragma unroll
  for (int cf = 0; cf < 4; ++cf) {
    int h = Cc + cf * 16 + cl;
    bb[cf] = b0[k * 128 + h];
    wv[cf] = w1[k * 128 + h];
  }
  float rs[4][4];
#pragma unroll
  for (int rf = 0; rf < 4; ++rf) {
#pragma unroll
    for (int r = 0; r < 4; ++r) {
      float s = 0.f;
#pragma unroll
      for (int cf = 0; cf < 4; ++cf) {
        float pre = acc[rf][cf][r] + bb[cf];
        s += wv[cf] * (1.f / (1.f + __expf(-pre)));
      }
      rs[rf][r] = s;
    }
  }
  // butterfly across the 16 column-lanes (C layout: col = lane&15)
#pragma unroll
  for (int m = 1; m <= 8; m <<= 1)
#pragma unroll
    for (int rf = 0; rf < 4; ++rf)
#pragma unroll
      for (int r = 0; r < 4; ++r)
        rs[rf][r] += __shfl_xor(rs[rf][r], m, 64);

  if (cl == 0) {
#pragma unroll
    for (int rf = 0; rf < 4; ++rf)
#pragma unroll
      for (int r = 0; r < 4; ++r)
        sRed[R + rf * 16 + q * 4 + r][wave & 1] = rs[rf][r];
  }
  __syncthreads();

  if (tid < 128) {
    float v = sRed[tid][0] + sRed[tid][1] + b1[k];
    if (*flag == 0) v = 1.f / (1.f + __expf(-v));  // binary-input path
    out[(size_t)(n0 + tid) * D_TOW + k] = v;
  }
}

extern "C" void kernel_launch(void* const* d_in, const int* in_sizes, int n_in,
                              void* d_out, int out_size, void* d_ws, size_t ws_size,
                              hipStream_t stream) {
  const float* x  = (const float*)d_in[0];
  const float* w0 = (const float*)d_in[1];
  const float* b0 = (const float*)d_in[2];
  const float* w1 = (const float*)d_in[3];
  const float* b1 = (const float*)d_in[4];
  float* out = (float*)d_out;

  char* ws = (char*)d_ws;
  int* flag = (int*)ws;
  ushort* xb  = (ushort*)(ws + 1024);                          // 2 MB
  ushort* w0b = (ushort*)(ws + 1024 + N_SAMP * D_TOW * 2);     // 4 MB

  hipMemsetAsync(flag, 0, 4, stream);

  int total4 = (N_SAMP * D_TOW + D_TOW * D_HID * D_TOW) / 4;   // 786432
  prep_kernel<<<total4 / 256, 256, 0, stream>>>(x, w0, xb, w0b, flag);

  towers_kernel<<<8192, 256, 0, stream>>>(xb, w0b, b0, w1, b1, flag, out);
}

// Round 2
// 137.733 us; speedup vs baseline: 1.3802x; 1.3802x over previous
//
#include <hip/hip_runtime.h>
#include <hip/hip_bf16.h>
#include <stdint.h>

#define N_SAMP 8192
#define D_TOW  128
#define D_HID  128

typedef __bf16 bf16x8 __attribute__((ext_vector_type(8)));
typedef float  f32x4  __attribute__((ext_vector_type(4)));

__device__ __forceinline__ ushort f2bf(float f) {
  union { float f; uint32_t u; } c; c.f = f;
  uint32_t u = c.u;
  return (ushort)((u + 0x7FFFu + ((u >> 16) & 1u)) >> 16);  // RNE
}

// sigmoid via raw HW ops: v_exp_f32 + v_rcp_f32 (5 instrs total).
// 1.f/x without fast-math lowers to the full IEEE div sequence (~10 instrs)
// and __expf may hit the accurate ocml path -- that was R1's VALU bloat.
__device__ __forceinline__ float fast_sigmoid(float p) {
  float e = __builtin_amdgcn_exp2f(p * -1.442695040888963f);
  return __builtin_amdgcn_rcpf(1.0f + e);
}

// fp32 -> bf16 convert for x and W0, fused binary-input check on x.
__global__ __launch_bounds__(256) void prep_kernel(
    const float* __restrict__ x, const float* __restrict__ w0,
    ushort* __restrict__ xb, ushort* __restrict__ w0b, int* __restrict__ flag) {
  const int NX4 = (N_SAMP * D_TOW) / 4;        // 262144
  const int NW4 = (D_TOW * D_HID * D_TOW) / 4; // 524288
  int t = blockIdx.x * blockDim.x + threadIdx.x;
  if (t < NX4) {
    float4 v = ((const float4*)x)[t];
    bool bad = !(((v.x == 0.f) || (v.x == 1.f)) &&
                 ((v.y == 0.f) || (v.y == 1.f)) &&
                 ((v.z == 0.f) || (v.z == 1.f)) &&
                 ((v.w == 0.f) || (v.w == 1.f)));
    ushort4 o;
    o.x = f2bf(v.x); o.y = f2bf(v.y); o.z = f2bf(v.z); o.w = f2bf(v.w);
    ((ushort4*)xb)[t] = o;
    if (__ballot(bad) != 0ull && (threadIdx.x & 63) == 0) *flag = 1;
  } else if (t < NX4 + NW4) {
    int j = t - NX4;
    float4 v = ((const float4*)w0)[j];
    ushort4 o;
    o.x = f2bf(v.x); o.y = f2bf(v.y); o.z = f2bf(v.z); o.w = f2bf(v.w);
    ((ushort4*)w0b)[j] = o;
  }
}

__device__ __forceinline__ void g2l16(const void* g, void* l) {
  __builtin_amdgcn_global_load_lds(
      (const __attribute__((address_space(1))) void*)g,
      (__attribute__((address_space(3))) void*)l, 16, 0, 0);
}

// One block = one tower k x one 128-row chunk of samples.
// Computes pre^T: A = W0_k [h x d], B = X^T (i.e. b-frags from X rows), so
// the MFMA C layout has row = h, col = n. Each lane then reduces its 16
// in-register h-values locally; cross-lane reduce is only 2 butterfly stages.
__global__ __launch_bounds__(256, 2) void towers_kernel(
    const ushort* __restrict__ xb, const ushort* __restrict__ w0b,
    const float* __restrict__ b0, const float* __restrict__ w1,
    const float* __restrict__ b1, const int* __restrict__ flag,
    float* __restrict__ out) {
  // [row][d], 128 rows x 256 B, 16B chunks XOR-swizzled by (row&15)
  __shared__ __align__(16) ushort sX[128 * 128];
  __shared__ __align__(16) ushort sW[128 * 128];
  __shared__ float sRed[128][2];

  int bid = blockIdx.x;
  int xcd = bid & 7;          // 16 towers per XCD for L2 locality
  int idx = bid >> 3;
  int k = xcd * 16 + (idx >> 6);
  int n0 = (idx & 63) * 128;

  int tid = threadIdx.x;
  int lane = tid & 63;
  int wave = tid >> 6;
  int q = lane >> 4;      // quad index (bits 4-5)
  int cl = lane & 15;

  const ushort* xg = xb + n0 * 128;          // [128][128] row-major bf16
  const ushort* wg = w0b + k * (128 * 128);  // W0_k: [h][d] row-major bf16

  // Stage both tiles. LDS dest = uniform base + lane*16 (HW rule); the XOR
  // swizzle is applied to the *global source* chunk so LDS[row][c] holds
  // global chunk c^(row&15). Still 256B-segment coalesced.
#pragma unroll
  for (int i = 0; i < 8; ++i) {
    int base = wave * 8192 + i * 1024;       // byte offset, wave-uniform
    int row = wave * 32 + i * 4 + q;         // this lane's row
    int c = cl ^ (row & 15);
    int off = row * 128 + c * 8;             // element offset
    g2l16(xg + off, (char*)sX + base);
    g2l16(wg + off, (char*)sW + base);
  }
  __syncthreads();

  int R  = (wave >> 1) * 64;   // n-quadrant
  int Ch = (wave & 1) * 64;    // h-quadrant

  f32x4 acc[4][4];             // [hf][nf]
#pragma unroll
  for (int hf = 0; hf < 4; ++hf)
#pragma unroll
    for (int nf = 0; nf < 4; ++nf)
      acc[hf][nf] = (f32x4){0.f, 0.f, 0.f, 0.f};

  // Row base byte-offsets, hoisted out of the K loop.
  int aBase[4], bBase[4];
#pragma unroll
  for (int f = 0; f < 4; ++f) {
    aBase[f] = (Ch + f * 16 + cl) * 256;     // W row = h
    bBase[f] = (R + f * 16 + cl) * 256;      // X row = n
  }

#pragma unroll
  for (int t = 0; t < 4; ++t) {  // K = 128 = 4 * 32
    int ch = ((t * 4 + q) ^ cl) << 4;        // swizzled 16B chunk offset
    bf16x8 a[4], b[4];
#pragma unroll
    for (int hf = 0; hf < 4; ++hf)
      a[hf] = *(const bf16x8*)((const char*)sW + aBase[hf] + ch);
#pragma unroll
    for (int nf = 0; nf < 4; ++nf)
      b[nf] = *(const bf16x8*)((const char*)sX + bBase[nf] + ch);
#pragma unroll
    for (int hf = 0; hf < 4; ++hf)
#pragma unroll
      for (int nf = 0; nf < 4; ++nf)
        acc[hf][nf] = __builtin_amdgcn_mfma_f32_16x16x32_bf16(
            a[hf], b[nf], acc[hf][nf], 0, 0, 0);
  }

  // Epilogue. C layout: col = n = R + nf*16 + cl ; row = h = Ch + hf*16 + q*4 + r.
  // Per-lane local reduce over 16 h-values, then 2-stage butterfly over q.
  f32x4 bb[4], wv[4];
#pragma unroll
  for (int hf = 0; hf < 4; ++hf) {
    int h = k * 128 + Ch + hf * 16 + q * 4;
    bb[hf] = *(const f32x4*)&b0[h];
    wv[hf] = *(const f32x4*)&w1[h];
  }
  float s[4] = {0.f, 0.f, 0.f, 0.f};
#pragma unroll
  for (int hf = 0; hf < 4; ++hf)
#pragma unroll
    for (int nf = 0; nf < 4; ++nf)
#pragma unroll
      for (int r = 0; r < 4; ++r)
        s[nf] += wv[hf][r] * fast_sigmoid(acc[hf][nf][r] + bb[hf][r]);

#pragma unroll
  for (int m = 16; m <= 32; m <<= 1)
#pragma unroll
    for (int nf = 0; nf < 4; ++nf)
      s[nf] += __shfl_xor(s[nf], m, 64);

  if (q == 0) {
#pragma unroll
    for (int nf = 0; nf < 4; ++nf)
      sRed[R + nf * 16 + cl][wave & 1] = s[nf];
  }
  __syncthreads();

  if (tid < 128) {
    float v = sRed[tid][0] + sRed[tid][1] + b1[k];
    if (*flag == 0) v = fast_sigmoid(v);  // binary-input path
    out[(size_t)(n0 + tid) * D_TOW + k] = v;
  }
}

extern "C" void kernel_launch(void* const* d_in, const int* in_sizes, int n_in,
                              void* d_out, int out_size, void* d_ws, size_t ws_size,
                              hipStream_t stream) {
  const float* x  = (const float*)d_in[0];
  const float* w0 = (const float*)d_in[1];
  const float* b0 = (const float*)d_in[2];
  const float* w1 = (const float*)d_in[3];
  const float* b1 = (const float*)d_in[4];
  float* out = (float*)d_out;

  char* ws = (char*)d_ws;
  int* flag = (int*)ws;
  ushort* xb  = (ushort*)(ws + 1024);                          // 2 MB
  ushort* w0b = (ushort*)(ws + 1024 + N_SAMP * D_TOW * 2);     // 4 MB

  hipMemsetAsync(flag, 0, 4, stream);

  int total4 = (N_SAMP * D_TOW + D_TOW * D_HID * D_TOW) / 4;   // 786432
  prep_kernel<<<total4 / 256, 256, 0, stream>>>(x, w0, xb, w0b, flag);

  towers_kernel<<<8192, 256, 0, stream>>>(xb, w0b, b0, w1, b1, flag, out);
}